// Round 15
// baseline (297.187 us; speedup 1.0000x reference)
//
#include <hip/hip_runtime.h>
#include <stdint.h>

#define IN_F  64
#define MID_F 128
#define OUT_F 32

typedef __bf16 bf16x8 __attribute__((ext_vector_type(8)));
typedef float  f32x4  __attribute__((ext_vector_type(4)));
typedef float  f32x2  __attribute__((ext_vector_type(2)));

static __device__ inline unsigned pack2(float a, float b) {
    unsigned short x = __builtin_bit_cast(unsigned short, (__bf16)a);
    unsigned short y = __builtin_bit_cast(unsigned short, (__bf16)b);
    return (unsigned)x | ((unsigned)y << 16);
}

// Packed 2xf32 atomic add: one memory-side RMW op instead of two.
// (Theory: the wall is RMW-op rate ~1/cycle/channel, not bytes.)
static __device__ inline void atomic_pk_add2(float* addr, float a, float b) {
#if __has_builtin(__builtin_amdgcn_global_atomic_fadd_v2f32)
    typedef __attribute__((address_space(1))) f32x2* gp2;
    f32x2 v = { a, b };
    __builtin_amdgcn_global_atomic_fadd_v2f32((gp2)(uintptr_t)addr, v);
#else
    atomicAdd(addr, a);
    atomicAdd(addr + 1, b);
#endif
}

// ---------------- weight prep: fragment-ordered bf16 (conflict-free LDS reads) ----------------
// w1frag (layer 1, swapped orientation): A=W1^T. frag f=t*2+q, lane l:
//   elem j = W1[k = q*32 + lg*8 + j][t*16 + lr]
// w2frag (layer 2, STANDARD orientation with k-permutation pi):
//   pi(q,lg,j) = ((j>>2)*4 + q)*16 + lg*4 + (j&3)
//   frag f2 = u*4+q, lane l: elem j = W2[pi(q,lg,j)][colmap(u,lr)]
// NEW colmap for packed atomics: column-slot (u,lr) holds TRUE feature 2*lr+u,
// so a lane's two outputs {acc2_0[r], acc2_1[r]} are CONSECUTIVE features
// {2lr, 2lr+1} of row lg*4+r -> one v2f32 atomic per row-pair.
__global__ void prep_kernel(const float* __restrict__ W1,
                            const float* __restrict__ W2,
                            unsigned* __restrict__ wbuf) {
    const int t = threadIdx.x;   // 1024 threads
    {
        const int i = t;
        const int f = i >> 6, l = i & 63;
        const int t1 = f >> 1, q = f & 1, lg = l >> 4, lr = l & 15;
        unsigned r[4];
        #pragma unroll
        for (int jj = 0; jj < 4; ++jj) {
            const int k0 = q * 32 + lg * 8 + 2 * jj;
            const float v0 = W1[(size_t)k0 * MID_F + t1 * 16 + lr];
            const float v1 = W1[(size_t)(k0 + 1) * MID_F + t1 * 16 + lr];
            r[jj] = pack2(v0, v1);
        }
        ((uint4*)wbuf)[i] = make_uint4(r[0], r[1], r[2], r[3]);
    }
    if (t < 512) {
        const int i = t;
        const int f = i >> 6, l = i & 63;
        const int u = f >> 2, q = f & 3, lg = l >> 4, lr = l & 15;
        const int pn = 2 * lr + u;              // packed-pair column map
        unsigned r[4];
        #pragma unroll
        for (int jj = 0; jj < 4; ++jj) {
            const int j0 = 2 * jj, j1 = 2 * jj + 1;
            const int ka = ((j0 >> 2) * 4 + q) * 16 + lg * 4 + (j0 & 3);
            const int kb = ((j1 >> 2) * 4 + q) * 16 + lg * 4 + (j1 & 3);
            r[jj] = pack2(W2[(size_t)ka * OUT_F + pn], W2[(size_t)kb * OUT_F + pn]);
        }
        ((uint4*)wbuf)[1024 + i] = make_uint4(r[0], r[1], r[2], r[3]);
    }
}

// ---------------- fused streaming MLP + packed coalesced atomic scatter ----------------
// r14 base (volatile LDS weights -> VGPR ~60, no spill, plain bounds) with the
// osum atomics packed 2xf32: 33.5M -> 16.8M memory-side RMW ops.
__global__ __launch_bounds__(512) void fused_mlp_scatter(
    const float* __restrict__ vecs,
    const int*   __restrict__ sidx,
    const unsigned* __restrict__ wbuf,
    const float* __restrict__ b1, const float* __restrict__ b2,
    float* __restrict__ osum, float* __restrict__ counts, int nrows)
{
    __shared__ __align__(16) __bf16 sW1F[16 * 64 * 8];   // 16 KB frag-ordered
    __shared__ __align__(16) __bf16 sW2F[8 * 64 * 8];    //  8 KB frag-ordered
    __shared__ __align__(16) float sB1[MID_F];
    __shared__ __align__(16) float sB2[OUT_F];

    const int tid = threadIdx.x;
    {   // linear 24 KB copy, coalesced, conflict-free
        const uint4* src = (const uint4*)wbuf;
        uint4* w1 = (uint4*)sW1F;
        uint4* w2 = (uint4*)sW2F;
        #pragma unroll
        for (int i = tid; i < 1024; i += 512) w1[i] = src[i];
        if (tid < 512) w2[tid] = src[1024 + tid];
        if (tid < MID_F) sB1[tid] = b1[tid];
        if (tid < OUT_F) sB2[tid] = b2[tid];
    }
    __syncthreads();

    const int lane = tid & 63, wid = tid >> 6;   // wid 0..7
    const int lg = lane >> 4, lr = lane & 15;

    // volatile views: forbid loop-invariant hoisting of weight/bias reads
    const volatile bf16x8* vW1 = (const volatile bf16x8*)sW1F;   // [frag*64+lane]
    const volatile bf16x8* vW2 = (const volatile bf16x8*)sW2F;
    const volatile f32x4*  vB1 = (const volatile f32x4*)sB1;     // [idx/4]

    const int nchunk = nrows >> 4;
    const int stride = gridDim.x * 8;

    // layer-2 bias for the lane's packed feature pair {2lr, 2lr+1}
    const float bz0 = sB2[2 * lr], bz1 = sB2[2 * lr + 1];

    for (int c = blockIdx.x * 8 + wid; c < nchunk; c += stride) {
        const int base = c << 4;

        // ---- coalesced x loads; f32 dies immediately into bf16 A-frags ----
        const float* xr = vecs + (size_t)(base + lr) * IN_F + lg * 8;
        bf16x8 a0, a1;
        {
            f32x4 x0a = *(const f32x4*)(xr);
            f32x4 x0b = *(const f32x4*)(xr + 4);
            f32x4 x1a = *(const f32x4*)(xr + 32);
            f32x4 x1b = *(const f32x4*)(xr + 36);
            #pragma unroll
            for (int j = 0; j < 4; ++j) {
                a0[j] = (__bf16)x0a[j]; a0[j + 4] = (__bf16)x0b[j];
                a1[j] = (__bf16)x1a[j]; a1[j + 4] = (__bf16)x1b[j];
            }
        }

        // ---- interleaved layers: per q, produce h-tiles q and q+4, consume
        //      them immediately in the layer-2 MFMA pair ----
        f32x4 acc2_0 = { bz0, bz0, bz0, bz0 };
        f32x4 acc2_1 = { bz1, bz1, bz1, bz1 };
        #pragma unroll
        for (int q = 0; q < 4; ++q) {
            // layer-1 tile t=q: lane owns h[row lr][feat q*16+lg*4+reg]
            bf16x8 w1a = vW1[(q * 2 + 0) * 64 + lane];
            bf16x8 w1b = vW1[(q * 2 + 1) * 64 + lane];
            f32x4 acc = vB1[(q * 16 + lg * 4) >> 2];
            acc = __builtin_amdgcn_mfma_f32_16x16x32_bf16(w1a, a0, acc, 0, 0, 0);
            acc = __builtin_amdgcn_mfma_f32_16x16x32_bf16(w1b, a1, acc, 0, 0, 0);
            const unsigned p0 = pack2(fmaxf(acc[0], 0.f), fmaxf(acc[1], 0.f));
            const unsigned p1 = pack2(fmaxf(acc[2], 0.f), fmaxf(acc[3], 0.f));
            // layer-1 tile t=q+4
            w1a = vW1[((q + 4) * 2 + 0) * 64 + lane];
            w1b = vW1[((q + 4) * 2 + 1) * 64 + lane];
            acc = vB1[((q + 4) * 16 + lg * 4) >> 2];
            acc = __builtin_amdgcn_mfma_f32_16x16x32_bf16(w1a, a0, acc, 0, 0, 0);
            acc = __builtin_amdgcn_mfma_f32_16x16x32_bf16(w1b, a1, acc, 0, 0, 0);
            const unsigned p2 = pack2(fmaxf(acc[0], 0.f), fmaxf(acc[1], 0.f));
            const unsigned p3 = pack2(fmaxf(acc[2], 0.f), fmaxf(acc[3], 0.f));
            // layer-2 q-slice (standard orientation, zero-shuffle via pi)
            uint4 bi = make_uint4(p0, p1, p2, p3);
            bf16x8 A2 = __builtin_bit_cast(bf16x8, bi);
            bf16x8 w2a = vW2[(0 * 4 + q) * 64 + lane];
            bf16x8 w2b = vW2[(1 * 4 + q) * 64 + lane];
            acc2_0 = __builtin_amdgcn_mfma_f32_16x16x32_bf16(A2, w2a, acc2_0, 0, 0, 0);
            acc2_1 = __builtin_amdgcn_mfma_f32_16x16x32_bf16(A2, w2b, acc2_1, 0, 0, 0);
        }

        // ---- segs loaded LATE (only the atomics need them) ----
        int4 segs = *(const int4*)(sidx + base + lg * 4);   // rows lg*4+0..3

        // ---- packed coalesced atomic scatter:
        //      per r: 16 lanes x one v2f32 = 128B contiguous per segment ----
        {
            const int sa[4] = { segs.x, segs.y, segs.z, segs.w };
            #pragma unroll
            for (int r = 0; r < 4; ++r) {
                float* o = osum + (size_t)sa[r] * OUT_F + 2 * lr;
                atomic_pk_add2(o, acc2_0[r], acc2_1[r]);
            }
            const int cs = (lr == 0) ? segs.x : (lr == 1) ? segs.y
                         : (lr == 2) ? segs.z : segs.w;
            if (lr < 4) atomicAdd(counts + cs, 1.0f);
        }
    }
}

__global__ __launch_bounds__(256) void finalize_kernel(
    float* __restrict__ osum, const float* __restrict__ counts, int total)
{
    int i = blockIdx.x * 256 + threadIdx.x;
    if (i < total) osum[i] = osum[i] / fmaxf(counts[i >> 5], 1.0f);
}

extern "C" void kernel_launch(void* const* d_in, const int* in_sizes, int n_in,
                              void* d_out, int out_size, void* d_ws, size_t ws_size,
                              hipStream_t stream)
{
    const float* vecs = (const float*)d_in[0];
    const int*   sidx = (const int*)d_in[1];
    const float* W1 = (const float*)d_in[3];
    const float* b1 = (const float*)d_in[4];
    const float* W2 = (const float*)d_in[5];
    const float* b2 = (const float*)d_in[6];
    float* osum = (float*)d_out;

    const int nrows = in_sizes[0] / IN_F;
    const int nseg  = out_size / OUT_F;

    // workspace: counts (nseg f32) + wbuf (24 KB)
    char* w = (char*)d_ws;
    float*    counts = (float*)w;
    unsigned* wbuf   = (unsigned*)(w + (((size_t)nseg * 4 + 255) & ~(size_t)255));

    hipMemsetAsync(osum,   0, (size_t)out_size * sizeof(float), stream);
    hipMemsetAsync(counts, 0, (size_t)nseg * sizeof(float), stream);

    prep_kernel<<<1, 1024, 0, stream>>>(W1, W2, wbuf);
    fused_mlp_scatter<<<1024, 512, 0, stream>>>(vecs, sidx, wbuf, b1, b2,
                                                osum, counts, nrows);
    finalize_kernel<<<(out_size + 255) / 256, 256, 0, stream>>>(osum, counts, out_size);
}

// Round 17
// 159.079 us; speedup vs baseline: 1.8682x; 1.8682x over previous
//
#include <hip/hip_runtime.h>
#include <hip/hip_fp16.h>
#include <stdint.h>

#define IN_F  64
#define MID_F 128
#define OUT_F 32

typedef __bf16 bf16x8 __attribute__((ext_vector_type(8)));
typedef float  f32x4  __attribute__((ext_vector_type(4)));

static __device__ inline unsigned pack2(float a, float b) {
    unsigned short x = __builtin_bit_cast(unsigned short, (__bf16)a);
    unsigned short y = __builtin_bit_cast(unsigned short, (__bf16)b);
    return (unsigned)x | ((unsigned)y << 16);
}

// Native packed-f16 atomic add (no return): one memory-side RMW op for two
// features. ROCm 7.2 lacks the atomicAdd(__half2*) overload (r16 compile
// fail), so emit the ISA instruction directly.
static __device__ inline void atomic_pk_add_h2(__half* addr, float a, float b) {
    const __half2 hv = __floats2half2_rn(a, b);
    const unsigned packed = __builtin_bit_cast(unsigned, hv);
    asm volatile("global_atomic_pk_add_f16 %0, %1, off"
                 :: "v"((void*)addr), "v"(packed)
                 : "memory");
}

// ---------------- weight prep: fragment-ordered bf16 (conflict-free LDS reads) ----------------
// w1frag (layer 1, swapped orientation): A=W1^T. frag f=t*2+q, lane l:
//   elem j = W1[k = q*32 + lg*8 + j][t*16 + lr]
// w2frag (layer 2, STANDARD orientation with k-permutation pi):
//   pi(q,lg,j) = ((j>>2)*4 + q)*16 + lg*4 + (j&3)
//   frag f2 = u*4+q, lane l: elem j = W2[pi(q,lg,j)][colmap(u,lr)]
// colmap (validated r15): column-slot (u,lr) holds TRUE feature 2*lr+u, so a
// lane's two outputs {acc2_0[r], acc2_1[r]} are CONSECUTIVE features
// {2lr, 2lr+1} of row lg*4+r -> one packed v2f16 atomic per row-pair.
__global__ void prep_kernel(const float* __restrict__ W1,
                            const float* __restrict__ W2,
                            unsigned* __restrict__ wbuf) {
    const int t = threadIdx.x;   // 1024 threads
    {
        const int i = t;
        const int f = i >> 6, l = i & 63;
        const int t1 = f >> 1, q = f & 1, lg = l >> 4, lr = l & 15;
        unsigned r[4];
        #pragma unroll
        for (int jj = 0; jj < 4; ++jj) {
            const int k0 = q * 32 + lg * 8 + 2 * jj;
            const float v0 = W1[(size_t)k0 * MID_F + t1 * 16 + lr];
            const float v1 = W1[(size_t)(k0 + 1) * MID_F + t1 * 16 + lr];
            r[jj] = pack2(v0, v1);
        }
        ((uint4*)wbuf)[i] = make_uint4(r[0], r[1], r[2], r[3]);
    }
    if (t < 512) {
        const int i = t;
        const int f = i >> 6, l = i & 63;
        const int u = f >> 2, q = f & 3, lg = l >> 4, lr = l & 15;
        const int pn = 2 * lr + u;              // packed-pair column map (r15-validated)
        unsigned r[4];
        #pragma unroll
        for (int jj = 0; jj < 4; ++jj) {
            const int j0 = 2 * jj, j1 = 2 * jj + 1;
            const int ka = ((j0 >> 2) * 4 + q) * 16 + lg * 4 + (j0 & 3);
            const int kb = ((j1 >> 2) * 4 + q) * 16 + lg * 4 + (j1 & 3);
            r[jj] = pack2(W2[(size_t)ka * OUT_F + pn], W2[(size_t)kb * OUT_F + pn]);
        }
        ((uint4*)wbuf)[1024 + i] = make_uint4(r[0], r[1], r[2], r[3]);
    }
}

// ---------------- fused streaming MLP + packed-f16 coalesced atomic scatter ----------------
// r14 base (volatile LDS weights -> VGPR ~60, no spill, plain bounds); osum
// accumulated in fp16 via native global_atomic_pk_add_f16:
// 33.5M scalar RMW ops -> 16.8M packed ops.
__global__ __launch_bounds__(512) void fused_mlp_scatter(
    const float* __restrict__ vecs,
    const int*   __restrict__ sidx,
    const unsigned* __restrict__ wbuf,
    const float* __restrict__ b1, const float* __restrict__ b2,
    __half* __restrict__ hsum, float* __restrict__ counts, int nrows)
{
    __shared__ __align__(16) __bf16 sW1F[16 * 64 * 8];   // 16 KB frag-ordered
    __shared__ __align__(16) __bf16 sW2F[8 * 64 * 8];    //  8 KB frag-ordered
    __shared__ __align__(16) float sB1[MID_F];
    __shared__ __align__(16) float sB2[OUT_F];

    const int tid = threadIdx.x;
    {   // linear 24 KB copy, coalesced, conflict-free
        const uint4* src = (const uint4*)wbuf;
        uint4* w1 = (uint4*)sW1F;
        uint4* w2 = (uint4*)sW2F;
        #pragma unroll
        for (int i = tid; i < 1024; i += 512) w1[i] = src[i];
        if (tid < 512) w2[tid] = src[1024 + tid];
        if (tid < MID_F) sB1[tid] = b1[tid];
        if (tid < OUT_F) sB2[tid] = b2[tid];
    }
    __syncthreads();

    const int lane = tid & 63, wid = tid >> 6;   // wid 0..7
    const int lg = lane >> 4, lr = lane & 15;

    // volatile views: forbid loop-invariant hoisting of weight/bias reads
    const volatile bf16x8* vW1 = (const volatile bf16x8*)sW1F;   // [frag*64+lane]
    const volatile bf16x8* vW2 = (const volatile bf16x8*)sW2F;
    const volatile f32x4*  vB1 = (const volatile f32x4*)sB1;     // [idx/4]

    const int nchunk = nrows >> 4;
    const int stride = gridDim.x * 8;

    // layer-2 bias for the lane's packed feature pair {2lr, 2lr+1}
    const float bz0 = sB2[2 * lr], bz1 = sB2[2 * lr + 1];

    for (int c = blockIdx.x * 8 + wid; c < nchunk; c += stride) {
        const int base = c << 4;

        // ---- coalesced x loads; f32 dies immediately into bf16 A-frags ----
        const float* xr = vecs + (size_t)(base + lr) * IN_F + lg * 8;
        bf16x8 a0, a1;
        {
            f32x4 x0a = *(const f32x4*)(xr);
            f32x4 x0b = *(const f32x4*)(xr + 4);
            f32x4 x1a = *(const f32x4*)(xr + 32);
            f32x4 x1b = *(const f32x4*)(xr + 36);
            #pragma unroll
            for (int j = 0; j < 4; ++j) {
                a0[j] = (__bf16)x0a[j]; a0[j + 4] = (__bf16)x0b[j];
                a1[j] = (__bf16)x1a[j]; a1[j + 4] = (__bf16)x1b[j];
            }
        }

        // ---- interleaved layers: per q, produce h-tiles q and q+4, consume
        //      them immediately in the layer-2 MFMA pair ----
        f32x4 acc2_0 = { bz0, bz0, bz0, bz0 };
        f32x4 acc2_1 = { bz1, bz1, bz1, bz1 };
        #pragma unroll
        for (int q = 0; q < 4; ++q) {
            // layer-1 tile t=q: lane owns h[row lr][feat q*16+lg*4+reg]
            bf16x8 w1a = vW1[(q * 2 + 0) * 64 + lane];
            bf16x8 w1b = vW1[(q * 2 + 1) * 64 + lane];
            f32x4 acc = vB1[(q * 16 + lg * 4) >> 2];
            acc = __builtin_amdgcn_mfma_f32_16x16x32_bf16(w1a, a0, acc, 0, 0, 0);
            acc = __builtin_amdgcn_mfma_f32_16x16x32_bf16(w1b, a1, acc, 0, 0, 0);
            const unsigned p0 = pack2(fmaxf(acc[0], 0.f), fmaxf(acc[1], 0.f));
            const unsigned p1 = pack2(fmaxf(acc[2], 0.f), fmaxf(acc[3], 0.f));
            // layer-1 tile t=q+4
            w1a = vW1[((q + 4) * 2 + 0) * 64 + lane];
            w1b = vW1[((q + 4) * 2 + 1) * 64 + lane];
            acc = vB1[((q + 4) * 16 + lg * 4) >> 2];
            acc = __builtin_amdgcn_mfma_f32_16x16x32_bf16(w1a, a0, acc, 0, 0, 0);
            acc = __builtin_amdgcn_mfma_f32_16x16x32_bf16(w1b, a1, acc, 0, 0, 0);
            const unsigned p2 = pack2(fmaxf(acc[0], 0.f), fmaxf(acc[1], 0.f));
            const unsigned p3 = pack2(fmaxf(acc[2], 0.f), fmaxf(acc[3], 0.f));
            // layer-2 q-slice (standard orientation, zero-shuffle via pi)
            uint4 bi = make_uint4(p0, p1, p2, p3);
            bf16x8 A2 = __builtin_bit_cast(bf16x8, bi);
            bf16x8 w2a = vW2[(0 * 4 + q) * 64 + lane];
            bf16x8 w2b = vW2[(1 * 4 + q) * 64 + lane];
            acc2_0 = __builtin_amdgcn_mfma_f32_16x16x32_bf16(A2, w2a, acc2_0, 0, 0, 0);
            acc2_1 = __builtin_amdgcn_mfma_f32_16x16x32_bf16(A2, w2b, acc2_1, 0, 0, 0);
        }

        // ---- segs loaded LATE (only the atomics need them) ----
        int4 segs = *(const int4*)(sidx + base + lg * 4);   // rows lg*4+0..3

        // ---- packed-f16 coalesced atomic scatter:
        //      per r: 16 lanes x one v2f16 (4B) = 64B contiguous per segment ----
        {
            const int sa[4] = { segs.x, segs.y, segs.z, segs.w };
            #pragma unroll
            for (int r = 0; r < 4; ++r) {
                atomic_pk_add_h2(hsum + (size_t)sa[r] * OUT_F + 2 * lr,
                                 acc2_0[r], acc2_1[r]);
            }
            const int cs = (lr == 0) ? segs.x : (lr == 1) ? segs.y
                         : (lr == 2) ? segs.z : segs.w;
            if (lr < 4) atomicAdd(counts + cs, 1.0f);
        }
    }
}

__global__ __launch_bounds__(256) void finalize_kernel(
    const __half* __restrict__ hsum, const float* __restrict__ counts,
    float* __restrict__ out, int total)
{
    int i = blockIdx.x * 256 + threadIdx.x;
    if (i < total) {
        const float s = __half2float(hsum[i]);
        out[i] = s / fmaxf(counts[i >> 5], 1.0f);
    }
}

extern "C" void kernel_launch(void* const* d_in, const int* in_sizes, int n_in,
                              void* d_out, int out_size, void* d_ws, size_t ws_size,
                              hipStream_t stream)
{
    const float* vecs = (const float*)d_in[0];
    const int*   sidx = (const int*)d_in[1];
    const float* W1 = (const float*)d_in[3];
    const float* b1 = (const float*)d_in[4];
    const float* W2 = (const float*)d_in[5];
    const float* b2 = (const float*)d_in[6];
    float* out = (float*)d_out;

    const int nrows = in_sizes[0] / IN_F;
    const int nseg  = out_size / OUT_F;

    // workspace: counts (nseg f32) + hsum (nseg*32 f16) + wbuf (24 KB)
    auto algn = [](size_t x) { return (x + 255) & ~(size_t)255; };
    char* w = (char*)d_ws;
    float*    counts = (float*)w;
    __half*   hsum   = (__half*)(w + algn((size_t)nseg * 4));
    unsigned* wbuf   = (unsigned*)(w + algn((size_t)nseg * 4)
                                     + algn((size_t)out_size * sizeof(__half)));

    hipMemsetAsync(counts, 0, (size_t)nseg * sizeof(float), stream);
    hipMemsetAsync(hsum,   0, (size_t)out_size * sizeof(__half), stream);

    prep_kernel<<<1, 1024, 0, stream>>>(W1, W2, wbuf);
    fused_mlp_scatter<<<1024, 512, 0, stream>>>(vecs, sidx, wbuf, b1, b2,
                                                hsum, counts, nrows);
    finalize_kernel<<<(out_size + 255) / 256, 256, 0, stream>>>(hsum, counts, out, out_size);
}

// Round 18
// 142.242 us; speedup vs baseline: 2.0893x; 1.1184x over previous
//
#include <hip/hip_runtime.h>
#include <hip/hip_fp16.h>
#include <stdint.h>

#define IN_F  64
#define MID_F 128
#define OUT_F 32

typedef __bf16 bf16x8 __attribute__((ext_vector_type(8)));
typedef float  f32x4  __attribute__((ext_vector_type(4)));

static __device__ inline unsigned pack2(float a, float b) {
    unsigned short x = __builtin_bit_cast(unsigned short, (__bf16)a);
    unsigned short y = __builtin_bit_cast(unsigned short, (__bf16)b);
    return (unsigned)x | ((unsigned)y << 16);
}

// Native packed-f16 atomic add (no return): one memory-side RMW op for two
// features; r17-measured: NOT write-through (hsum stays cache-resident).
static __device__ inline void atomic_pk_add_h2(__half* addr, float a, float b) {
    const __half2 hv = __floats2half2_rn(a, b);
    const unsigned packed = __builtin_bit_cast(unsigned, hv);
    asm volatile("global_atomic_pk_add_f16 %0, %1, off"
                 :: "v"((void*)addr), "v"(packed)
                 : "memory");
}

// ---------------- weight prep: fragment-ordered bf16 (conflict-free LDS reads) ----------------
// w1frag (layer 1, swapped orientation): A=W1^T. frag f=t*2+q, lane l:
//   elem j = W1[k = q*32 + lg*8 + j][t*16 + lr]
// w2frag (layer 2, STANDARD orientation with k-permutation pi):
//   pi(q,lg,j) = ((j>>2)*4 + q)*16 + lg*4 + (j&3)
//   frag f2 = u*4+q, lane l: elem j = W2[pi(q,lg,j)][colmap(u,lr)]
// colmap (r15/r17-validated): column-slot (u,lr) holds TRUE feature 2*lr+u, so
// a lane's two outputs are CONSECUTIVE features {2lr,2lr+1} of row lg*4+r
// -> one packed v2f16 atomic per row-pair, 16 lanes x 4B = 64B/line/segment.
__global__ void prep_kernel(const float* __restrict__ W1,
                            const float* __restrict__ W2,
                            unsigned* __restrict__ wbuf) {
    const int t = threadIdx.x;   // 1024 threads
    {
        const int i = t;
        const int f = i >> 6, l = i & 63;
        const int t1 = f >> 1, q = f & 1, lg = l >> 4, lr = l & 15;
        unsigned r[4];
        #pragma unroll
        for (int jj = 0; jj < 4; ++jj) {
            const int k0 = q * 32 + lg * 8 + 2 * jj;
            const float v0 = W1[(size_t)k0 * MID_F + t1 * 16 + lr];
            const float v1 = W1[(size_t)(k0 + 1) * MID_F + t1 * 16 + lr];
            r[jj] = pack2(v0, v1);
        }
        ((uint4*)wbuf)[i] = make_uint4(r[0], r[1], r[2], r[3]);
    }
    if (t < 512) {
        const int i = t;
        const int f = i >> 6, l = i & 63;
        const int u = f >> 2, q = f & 3, lg = l >> 4, lr = l & 15;
        const int pn = 2 * lr + u;              // packed-pair column map
        unsigned r[4];
        #pragma unroll
        for (int jj = 0; jj < 4; ++jj) {
            const int j0 = 2 * jj, j1 = 2 * jj + 1;
            const int ka = ((j0 >> 2) * 4 + q) * 16 + lg * 4 + (j0 & 3);
            const int kb = ((j1 >> 2) * 4 + q) * 16 + lg * 4 + (j1 & 3);
            r[jj] = pack2(W2[(size_t)ka * OUT_F + pn], W2[(size_t)kb * OUT_F + pn]);
        }
        ((uint4*)wbuf)[1024 + i] = make_uint4(r[0], r[1], r[2], r[3]);
    }
}

// ---------------- fused streaming MLP, ONE CHUNK PER WAVE (no loop) ----------------
// Theory (r17): in-order vmcnt retirement puts the atomic-ack latency on every
// loop iteration's critical path (older atomics gate the younger x-load wait).
// Fix: no loop. Each wave processes exactly 16 rows and exits; atomics are the
// last VMEM ops before s_endpgm (no drain needed). The coherent-point latency
// overlaps the NEXT block's waves via CU slot refill (wave churn), not vmcnt.
__global__ __launch_bounds__(512) void fused_mlp_scatter(
    const float* __restrict__ vecs,
    const int*   __restrict__ sidx,
    const unsigned* __restrict__ wbuf,
    const float* __restrict__ b1, const float* __restrict__ b2,
    __half* __restrict__ hsum, float* __restrict__ counts, int nrows)
{
    __shared__ __align__(16) __bf16 sW1F[16 * 64 * 8];   // 16 KB frag-ordered
    __shared__ __align__(16) __bf16 sW2F[8 * 64 * 8];    //  8 KB frag-ordered
    __shared__ __align__(16) float sB1[MID_F];
    __shared__ __align__(16) float sB2[OUT_F];

    const int tid = threadIdx.x;
    {   // linear 24 KB copy, coalesced, conflict-free (wbuf is L2/L3-resident)
        const uint4* src = (const uint4*)wbuf;
        uint4* w1 = (uint4*)sW1F;
        uint4* w2 = (uint4*)sW2F;
        #pragma unroll
        for (int i = tid; i < 1024; i += 512) w1[i] = src[i];
        if (tid < 512) w2[tid] = src[1024 + tid];
        if (tid < MID_F) sB1[tid] = b1[tid];
        if (tid < OUT_F) sB2[tid] = b2[tid];
    }
    __syncthreads();

    const int lane = tid & 63, wid = tid >> 6;   // wid 0..7
    const int lg = lane >> 4, lr = lane & 15;

    // one chunk per wave
    const int c = blockIdx.x * 8 + wid;
    if (c >= (nrows >> 4)) return;
    const int base = c << 4;

    // ---- coalesced x loads; f32 dies immediately into bf16 A-frags ----
    const float* xr = vecs + (size_t)(base + lr) * IN_F + lg * 8;
    bf16x8 a0, a1;
    {
        f32x4 x0a = *(const f32x4*)(xr);
        f32x4 x0b = *(const f32x4*)(xr + 4);
        f32x4 x1a = *(const f32x4*)(xr + 32);
        f32x4 x1b = *(const f32x4*)(xr + 36);
        #pragma unroll
        for (int j = 0; j < 4; ++j) {
            a0[j] = (__bf16)x0a[j]; a0[j + 4] = (__bf16)x0b[j];
            a1[j] = (__bf16)x1a[j]; a1[j + 4] = (__bf16)x1b[j];
        }
    }

    const bf16x8* W1F = (const bf16x8*)sW1F;
    const bf16x8* W2F = (const bf16x8*)sW2F;

    // ---- interleaved layers: per q, produce h-tiles q and q+4, consume
    //      them immediately in the layer-2 MFMA pair ----
    const float bz0 = sB2[2 * lr], bz1 = sB2[2 * lr + 1];
    f32x4 acc2_0 = { bz0, bz0, bz0, bz0 };
    f32x4 acc2_1 = { bz1, bz1, bz1, bz1 };
    #pragma unroll
    for (int q = 0; q < 4; ++q) {
        // layer-1 tile t=q: lane owns h[row lr][feat q*16+lg*4+reg]
        bf16x8 w1a = W1F[(q * 2 + 0) * 64 + lane];
        bf16x8 w1b = W1F[(q * 2 + 1) * 64 + lane];
        f32x4 acc = *(const f32x4*)&sB1[q * 16 + lg * 4];
        acc = __builtin_amdgcn_mfma_f32_16x16x32_bf16(w1a, a0, acc, 0, 0, 0);
        acc = __builtin_amdgcn_mfma_f32_16x16x32_bf16(w1b, a1, acc, 0, 0, 0);
        const unsigned p0 = pack2(fmaxf(acc[0], 0.f), fmaxf(acc[1], 0.f));
        const unsigned p1 = pack2(fmaxf(acc[2], 0.f), fmaxf(acc[3], 0.f));
        // layer-1 tile t=q+4
        w1a = W1F[((q + 4) * 2 + 0) * 64 + lane];
        w1b = W1F[((q + 4) * 2 + 1) * 64 + lane];
        acc = *(const f32x4*)&sB1[(q + 4) * 16 + lg * 4];
        acc = __builtin_amdgcn_mfma_f32_16x16x32_bf16(w1a, a0, acc, 0, 0, 0);
        acc = __builtin_amdgcn_mfma_f32_16x16x32_bf16(w1b, a1, acc, 0, 0, 0);
        const unsigned p2 = pack2(fmaxf(acc[0], 0.f), fmaxf(acc[1], 0.f));
        const unsigned p3 = pack2(fmaxf(acc[2], 0.f), fmaxf(acc[3], 0.f));
        // layer-2 q-slice (standard orientation, zero-shuffle via pi)
        uint4 bi = make_uint4(p0, p1, p2, p3);
        bf16x8 A2 = __builtin_bit_cast(bf16x8, bi);
        bf16x8 w2a = W2F[(0 * 4 + q) * 64 + lane];
        bf16x8 w2b = W2F[(1 * 4 + q) * 64 + lane];
        acc2_0 = __builtin_amdgcn_mfma_f32_16x16x32_bf16(A2, w2a, acc2_0, 0, 0, 0);
        acc2_1 = __builtin_amdgcn_mfma_f32_16x16x32_bf16(A2, w2b, acc2_1, 0, 0, 0);
    }

    // ---- segs loaded late; atomics are the LAST VMEM ops before wave exit ----
    int4 segs = *(const int4*)(sidx + base + lg * 4);   // rows lg*4+0..3
    {
        const int sa[4] = { segs.x, segs.y, segs.z, segs.w };
        #pragma unroll
        for (int r = 0; r < 4; ++r) {
            atomic_pk_add_h2(hsum + (size_t)sa[r] * OUT_F + 2 * lr,
                             acc2_0[r], acc2_1[r]);
        }
        const int cs = (lr == 0) ? segs.x : (lr == 1) ? segs.y
                     : (lr == 2) ? segs.z : segs.w;
        if (lr < 4) atomicAdd(counts + cs, 1.0f);
    }
}

__global__ __launch_bounds__(256) void finalize_kernel(
    const __half* __restrict__ hsum, const float* __restrict__ counts,
    float* __restrict__ out, int total)
{
    int i = blockIdx.x * 256 + threadIdx.x;
    if (i < total) {
        const float s = __half2float(hsum[i]);
        out[i] = s / fmaxf(counts[i >> 5], 1.0f);
    }
}

extern "C" void kernel_launch(void* const* d_in, const int* in_sizes, int n_in,
                              void* d_out, int out_size, void* d_ws, size_t ws_size,
                              hipStream_t stream)
{
    const float* vecs = (const float*)d_in[0];
    const int*   sidx = (const int*)d_in[1];
    const float* W1 = (const float*)d_in[3];
    const float* b1 = (const float*)d_in[4];
    const float* W2 = (const float*)d_in[5];
    const float* b2 = (const float*)d_in[6];
    float* out = (float*)d_out;

    const int nrows = in_sizes[0] / IN_F;
    const int nseg  = out_size / OUT_F;
    const int nchunk = nrows >> 4;
    const int nblk   = (nchunk + 7) / 8;   // 8 waves/block, 1 chunk/wave

    // workspace: counts (nseg f32) + hsum (nseg*32 f16) + wbuf (24 KB)
    auto algn = [](size_t x) { return (x + 255) & ~(size_t)255; };
    char* w = (char*)d_ws;
    float*    counts = (float*)w;
    __half*   hsum   = (__half*)(w + algn((size_t)nseg * 4));
    unsigned* wbuf   = (unsigned*)(w + algn((size_t)nseg * 4)
                                     + algn((size_t)out_size * sizeof(__half)));

    hipMemsetAsync(counts, 0, (size_t)nseg * sizeof(float), stream);
    hipMemsetAsync(hsum,   0, (size_t)out_size * sizeof(__half), stream);

    prep_kernel<<<1, 1024, 0, stream>>>(W1, W2, wbuf);
    fused_mlp_scatter<<<nblk, 512, 0, stream>>>(vecs, sidx, wbuf, b1, b2,
                                                hsum, counts, nrows);
    finalize_kernel<<<(out_size + 255) / 256, 256, 0, stream>>>(hsum, counts, out, out_size);
}

// Round 19
// 134.620 us; speedup vs baseline: 2.2076x; 1.0566x over previous
//
#include <hip/hip_runtime.h>
#include <hip/hip_fp16.h>
#include <stdint.h>

#define IN_F  64
#define MID_F 128
#define OUT_F 32

typedef __bf16 bf16x8 __attribute__((ext_vector_type(8)));
typedef float  f32x4  __attribute__((ext_vector_type(4)));

static __device__ inline unsigned pack2(float a, float b) {
    unsigned short x = __builtin_bit_cast(unsigned short, (__bf16)a);
    unsigned short y = __builtin_bit_cast(unsigned short, (__bf16)b);
    return (unsigned)x | ((unsigned)y << 16);
}

// Native packed-f16 atomic add (no return): one memory-side RMW op for two
// features; r17-measured: NOT write-through (hsum stays cache-resident).
static __device__ inline void atomic_pk_add_h2(__half* addr, float a, float b) {
    const __half2 hv = __floats2half2_rn(a, b);
    const unsigned packed = __builtin_bit_cast(unsigned, hv);
    asm volatile("global_atomic_pk_add_f16 %0, %1, off"
                 :: "v"((void*)addr), "v"(packed)
                 : "memory");
}

// ---------------- combined prep + zero kernel (one dispatch) ----------------
// Block 0: build fragment-ordered bf16 weights. r18's version did 16K
// uncoalesced 512B-stride global reads from ONE block (~10-25us serial stream
// time). Fix: stage W1/W2 into LDS with coalesced linear reads first, then
// do the scattered fragment gather from LDS (free).
// Blocks 1..64: zero counts+hsum (replaces two hipMemsetAsync dispatches).
//
// Fragment layouts (validated r9/r15/r17):
// w1frag (layer 1, swapped): frag f=t*2+q, lane l: elem j = W1[q*32+lg*8+j][t*16+lr]
// w2frag (layer 2, standard + pi k-map): frag f2=u*4+q, lane l:
//   elem j = W2[((j>>2)*4+q)*16+lg*4+(j&3)][2*lr+u]   (packed-pair column map)
__global__ void prep_zero_kernel(const float* __restrict__ W1,
                                 const float* __restrict__ W2,
                                 unsigned* __restrict__ wbuf,
                                 uint4* __restrict__ zbase, int zlen16) {
    const int t = threadIdx.x;   // 1024 threads

    if (blockIdx.x != 0) {
        // ---- zero counts + hsum, grid-stride uint4 stores ----
        const uint4 zero = make_uint4(0u, 0u, 0u, 0u);
        for (int i = (blockIdx.x - 1) * 1024 + t; i < zlen16; i += 64 * 1024)
            zbase[i] = zero;
        return;
    }

    // ---- block 0: weight prep, LDS-staged ----
    __shared__ float sW1raw[IN_F * MID_F];   // 32 KB
    __shared__ float sW2raw[MID_F * OUT_F];  // 16 KB

    for (int i = t; i < IN_F * MID_F; i += 1024) sW1raw[i] = W1[i];
    for (int i = t; i < MID_F * OUT_F; i += 1024) sW2raw[i] = W2[i];
    __syncthreads();

    {
        const int i = t;
        const int f = i >> 6, l = i & 63;
        const int t1 = f >> 1, q = f & 1, lg = l >> 4, lr = l & 15;
        unsigned r[4];
        #pragma unroll
        for (int jj = 0; jj < 4; ++jj) {
            const int k0 = q * 32 + lg * 8 + 2 * jj;
            const float v0 = sW1raw[k0 * MID_F + t1 * 16 + lr];
            const float v1 = sW1raw[(k0 + 1) * MID_F + t1 * 16 + lr];
            r[jj] = pack2(v0, v1);
        }
        ((uint4*)wbuf)[i] = make_uint4(r[0], r[1], r[2], r[3]);
    }
    if (t < 512) {
        const int i = t;
        const int f = i >> 6, l = i & 63;
        const int u = f >> 2, q = f & 3, lg = l >> 4, lr = l & 15;
        const int pn = 2 * lr + u;              // packed-pair column map
        unsigned r[4];
        #pragma unroll
        for (int jj = 0; jj < 4; ++jj) {
            const int j0 = 2 * jj, j1 = 2 * jj + 1;
            const int ka = ((j0 >> 2) * 4 + q) * 16 + lg * 4 + (j0 & 3);
            const int kb = ((j1 >> 2) * 4 + q) * 16 + lg * 4 + (j1 & 3);
            r[jj] = pack2(sW2raw[ka * OUT_F + pn], sW2raw[kb * OUT_F + pn]);
        }
        ((uint4*)wbuf)[1024 + i] = make_uint4(r[0], r[1], r[2], r[3]);
    }
}

// ---------------- fused streaming MLP, ONE CHUNK PER WAVE (r18, unchanged) ----------------
// In-order vmcnt retirement puts atomic-ack latency on any loop's critical
// path; with no loop, atomics are the last VMEM ops before s_endpgm and the
// coherent-point latency overlaps the next blocks' waves via slot refill.
__global__ __launch_bounds__(512) void fused_mlp_scatter(
    const float* __restrict__ vecs,
    const int*   __restrict__ sidx,
    const unsigned* __restrict__ wbuf,
    const float* __restrict__ b1, const float* __restrict__ b2,
    __half* __restrict__ hsum, float* __restrict__ counts, int nrows)
{
    __shared__ __align__(16) __bf16 sW1F[16 * 64 * 8];   // 16 KB frag-ordered
    __shared__ __align__(16) __bf16 sW2F[8 * 64 * 8];    //  8 KB frag-ordered
    __shared__ __align__(16) float sB1[MID_F];
    __shared__ __align__(16) float sB2[OUT_F];

    const int tid = threadIdx.x;
    {   // linear 24 KB copy, coalesced, conflict-free (wbuf is L2/L3-resident)
        const uint4* src = (const uint4*)wbuf;
        uint4* w1 = (uint4*)sW1F;
        uint4* w2 = (uint4*)sW2F;
        #pragma unroll
        for (int i = tid; i < 1024; i += 512) w1[i] = src[i];
        if (tid < 512) w2[tid] = src[1024 + tid];
        if (tid < MID_F) sB1[tid] = b1[tid];
        if (tid < OUT_F) sB2[tid] = b2[tid];
    }
    __syncthreads();

    const int lane = tid & 63, wid = tid >> 6;   // wid 0..7
    const int lg = lane >> 4, lr = lane & 15;

    // one chunk per wave
    const int c = blockIdx.x * 8 + wid;
    if (c >= (nrows >> 4)) return;
    const int base = c << 4;

    // ---- coalesced x loads; f32 dies immediately into bf16 A-frags ----
    const float* xr = vecs + (size_t)(base + lr) * IN_F + lg * 8;
    bf16x8 a0, a1;
    {
        f32x4 x0a = *(const f32x4*)(xr);
        f32x4 x0b = *(const f32x4*)(xr + 4);
        f32x4 x1a = *(const f32x4*)(xr + 32);
        f32x4 x1b = *(const f32x4*)(xr + 36);
        #pragma unroll
        for (int j = 0; j < 4; ++j) {
            a0[j] = (__bf16)x0a[j]; a0[j + 4] = (__bf16)x0b[j];
            a1[j] = (__bf16)x1a[j]; a1[j + 4] = (__bf16)x1b[j];
        }
    }

    const bf16x8* W1F = (const bf16x8*)sW1F;
    const bf16x8* W2F = (const bf16x8*)sW2F;

    // ---- interleaved layers: per q, produce h-tiles q and q+4, consume
    //      them immediately in the layer-2 MFMA pair ----
    const float bz0 = sB2[2 * lr], bz1 = sB2[2 * lr + 1];
    f32x4 acc2_0 = { bz0, bz0, bz0, bz0 };
    f32x4 acc2_1 = { bz1, bz1, bz1, bz1 };
    #pragma unroll
    for (int q = 0; q < 4; ++q) {
        // layer-1 tile t=q: lane owns h[row lr][feat q*16+lg*4+reg]
        bf16x8 w1a = W1F[(q * 2 + 0) * 64 + lane];
        bf16x8 w1b = W1F[(q * 2 + 1) * 64 + lane];
        f32x4 acc = *(const f32x4*)&sB1[q * 16 + lg * 4];
        acc = __builtin_amdgcn_mfma_f32_16x16x32_bf16(w1a, a0, acc, 0, 0, 0);
        acc = __builtin_amdgcn_mfma_f32_16x16x32_bf16(w1b, a1, acc, 0, 0, 0);
        const unsigned p0 = pack2(fmaxf(acc[0], 0.f), fmaxf(acc[1], 0.f));
        const unsigned p1 = pack2(fmaxf(acc[2], 0.f), fmaxf(acc[3], 0.f));
        // layer-1 tile t=q+4
        w1a = W1F[((q + 4) * 2 + 0) * 64 + lane];
        w1b = W1F[((q + 4) * 2 + 1) * 64 + lane];
        acc = *(const f32x4*)&sB1[(q + 4) * 16 + lg * 4];
        acc = __builtin_amdgcn_mfma_f32_16x16x32_bf16(w1a, a0, acc, 0, 0, 0);
        acc = __builtin_amdgcn_mfma_f32_16x16x32_bf16(w1b, a1, acc, 0, 0, 0);
        const unsigned p2 = pack2(fmaxf(acc[0], 0.f), fmaxf(acc[1], 0.f));
        const unsigned p3 = pack2(fmaxf(acc[2], 0.f), fmaxf(acc[3], 0.f));
        // layer-2 q-slice (standard orientation, zero-shuffle via pi)
        uint4 bi = make_uint4(p0, p1, p2, p3);
        bf16x8 A2 = __builtin_bit_cast(bf16x8, bi);
        bf16x8 w2a = W2F[(0 * 4 + q) * 64 + lane];
        bf16x8 w2b = W2F[(1 * 4 + q) * 64 + lane];
        acc2_0 = __builtin_amdgcn_mfma_f32_16x16x32_bf16(A2, w2a, acc2_0, 0, 0, 0);
        acc2_1 = __builtin_amdgcn_mfma_f32_16x16x32_bf16(A2, w2b, acc2_1, 0, 0, 0);
    }

    // ---- segs loaded late; atomics are the LAST VMEM ops before wave exit ----
    int4 segs = *(const int4*)(sidx + base + lg * 4);   // rows lg*4+0..3
    {
        const int sa[4] = { segs.x, segs.y, segs.z, segs.w };
        #pragma unroll
        for (int r = 0; r < 4; ++r) {
            atomic_pk_add_h2(hsum + (size_t)sa[r] * OUT_F + 2 * lr,
                             acc2_0[r], acc2_1[r]);
        }
        const int cs = (lr == 0) ? segs.x : (lr == 1) ? segs.y
                     : (lr == 2) ? segs.z : segs.w;
        if (lr < 4) atomicAdd(counts + cs, 1.0f);
    }
}

__global__ __launch_bounds__(256) void finalize_kernel(
    const __half* __restrict__ hsum, const float* __restrict__ counts,
    float* __restrict__ out, int total)
{
    int i = blockIdx.x * 256 + threadIdx.x;
    if (i < total) {
        const float s = __half2float(hsum[i]);
        out[i] = s / fmaxf(counts[i >> 5], 1.0f);
    }
}

extern "C" void kernel_launch(void* const* d_in, const int* in_sizes, int n_in,
                              void* d_out, int out_size, void* d_ws, size_t ws_size,
                              hipStream_t stream)
{
    const float* vecs = (const float*)d_in[0];
    const int*   sidx = (const int*)d_in[1];
    const float* W1 = (const float*)d_in[3];
    const float* b1 = (const float*)d_in[4];
    const float* W2 = (const float*)d_in[5];
    const float* b2 = (const float*)d_in[6];
    float* out = (float*)d_out;

    const int nrows = in_sizes[0] / IN_F;
    const int nseg  = out_size / OUT_F;
    const int nchunk = nrows >> 4;
    const int nblk   = (nchunk + 7) / 8;   // 8 waves/block, 1 chunk/wave

    // workspace layout: [counts nseg*f32][hsum out_size*f16][wbuf 24KB]
    auto algn = [](size_t x) { return (x + 255) & ~(size_t)255; };
    char* w = (char*)d_ws;
    const size_t counts_b = algn((size_t)nseg * 4);
    const size_t hsum_b   = algn((size_t)out_size * sizeof(__half));
    float*    counts = (float*)w;
    __half*   hsum   = (__half*)(w + counts_b);
    unsigned* wbuf   = (unsigned*)(w + counts_b + hsum_b);

    const int zlen16 = (int)((counts_b + hsum_b) / 16);   // uint4 count (256-aligned)

    prep_zero_kernel<<<65, 1024, 0, stream>>>(W1, W2, wbuf, (uint4*)w, zlen16);
    fused_mlp_scatter<<<nblk, 512, 0, stream>>>(vecs, sidx, wbuf, b1, b2,
                                                hsum, counts, nrows);
    finalize_kernel<<<(out_size + 255) / 256, 256, 0, stream>>>(hsum, counts, out, out_size);
}